// Round 7
// baseline (322.032 us; speedup 1.0000x reference)
//
#include <hip/hip_runtime.h>
#include <math.h>

typedef float f32x4 __attribute__((ext_vector_type(4)));
typedef short bf16x8 __attribute__((ext_vector_type(8)));
typedef unsigned int u32;

#define SCALE 4.48798950512827605495f  // 2*pi/1.4

// ---- workspace layout (bytes) ----
#define SCORES_OFF 0              // f32 [270][288]
#define WH_OFF     311040         // bf16 [288][288]
#define WL_OFF     476928         // bf16 [288][288]
#define EMBH_OFF   642816         // bf16 [270][2048]
#define HEADSH_OFF 1748736        // bf16 [270][2048]

__device__ __forceinline__ unsigned short bf16rn(float f) {
    unsigned int u = __float_as_uint(f);
    u += 0x7FFFu + ((u >> 16) & 1u);
    return (unsigned short)(u >> 16);
}

// -------- Kernel 1: prep — emb rows (bf16) + heads convert (bf16) --------
__global__ void prep_kernel(const float* __restrict__ layout,
                            const float* __restrict__ heads,
                            unsigned short* __restrict__ embh,
                            unsigned short* __restrict__ headsh) {
    int blk = blockIdx.x;
    if (blk < 270) {
        int c = blk;
        float px = (layout[2 * c] + 0.2f) * SCALE;
        float py = (layout[2 * c + 1] + 0.2f) * SCALE;
        unsigned short* row = embh + (size_t)c * 2048;
        for (int q = threadIdx.x; q < 1024; q += blockDim.x) {
            int i = q >> 5, j = q & 31;
            float loc = px * (float)i + py * (float)j;
            float s, co;
            sincosf(loc, &s, &co);
            row[q] = bf16rn(co);
            row[1024 + q] = bf16rn(s);
        }
    } else {
        int o = blk - 270;
        const float* src = heads + (size_t)o * 2048;
        unsigned short* dst = headsh + (size_t)o * 2048;
        for (int q = threadIdx.x; q < 2048; q += blockDim.x)
            dst[q] = bf16rn(src[q]);
    }
}

// -------- Kernel 2: scores = heads @ emb^T, 4-wave k-split + LDS reduce --------
__global__ __launch_bounds__(256) void scores_kernel(
    const unsigned short* __restrict__ headsh,
    const unsigned short* __restrict__ embh,
    float* __restrict__ scores)
{
    __shared__ float red[4][64][16];
    const int ot = blockIdx.x, ct = blockIdx.y;
    const int tid = threadIdx.x;
    const int w = tid >> 6, lane = tid & 63;
    const int lhi = lane >> 4, llo = lane & 15;

    f32x4 acc[2][2];
    #pragma unroll
    for (int m = 0; m < 2; ++m)
        #pragma unroll
        for (int n = 0; n < 2; ++n) acc[m][n] = (f32x4){0.f, 0.f, 0.f, 0.f};

    int arow[2], crow[2];
    #pragma unroll
    for (int m = 0; m < 2; ++m) {
        int r = ot * 32 + m * 16 + llo; arow[m] = (r > 269) ? 269 : r;
        int c = ct * 32 + m * 16 + llo; crow[m] = (c > 269) ? 269 : c;
    }

    for (int s = 0; s < 16; ++s) {
        int kk = w * 512 + s * 32 + lhi * 8;
        bf16x8 a[2], bb[2];
        #pragma unroll
        for (int m = 0; m < 2; ++m)
            a[m] = *(const bf16x8*)(headsh + (size_t)arow[m] * 2048 + kk);
        #pragma unroll
        for (int n = 0; n < 2; ++n)
            bb[n] = *(const bf16x8*)(embh + (size_t)crow[n] * 2048 + kk);
        #pragma unroll
        for (int m = 0; m < 2; ++m)
            #pragma unroll
            for (int n = 0; n < 2; ++n)
                acc[m][n] = __builtin_amdgcn_mfma_f32_16x16x32_bf16(a[m], bb[n], acc[m][n], 0, 0, 0);
    }

    #pragma unroll
    for (int m = 0; m < 2; ++m)
        #pragma unroll
        for (int n = 0; n < 2; ++n)
            #pragma unroll
            for (int r = 0; r < 4; ++r)
                red[w][lane][m * 8 + n * 4 + r] = acc[m][n][r];
    __syncthreads();
    if (w == 0) {
        #pragma unroll
        for (int m = 0; m < 2; ++m)
            #pragma unroll
            for (int n = 0; n < 2; ++n)
                #pragma unroll
                for (int r = 0; r < 4; ++r) {
                    int idx = m * 8 + n * 4 + r;
                    float sum = red[0][lane][idx] + red[1][lane][idx]
                              + red[2][lane][idx] + red[3][lane][idx];
                    int row = ot * 32 + m * 16 + lhi * 4 + r;
                    int col = ct * 32 + n * 16 + llo;
                    if (row < 270 && col < 270)
                        scores[row * 288 + col] = sum;
                }
    }
}

// -------- Kernel 3: softmax over c; writes Wh/Wl bf16 [288][288] zero-padded --------
__global__ void softmax_kernel(const float* __restrict__ scores,
                               const float* __restrict__ layout,
                               unsigned short* __restrict__ Wh,
                               unsigned short* __restrict__ Wl) {
    int o = blockIdx.x;          // 0..287
    int lane = threadIdx.x;      // 64
    unsigned short* wh = Wh + (size_t)o * 288;
    unsigned short* wl = Wl + (size_t)o * 288;
    if (o >= 270) {
        for (int c = lane; c < 288; c += 64) { wh[c] = 0; wl[c] = 0; }
        return;
    }
    float v[5]; int cs[5]; int n = 0;
    float m = -INFINITY;
    for (int c = lane; c < 270; c += 64) {
        float s = scores[o * 288 + c];
        bool inv = (layout[c * 2] == -0.1f) && (layout[c * 2 + 1] == -0.1f);
        if (inv) s = -INFINITY;
        v[n] = s; cs[n] = c; n++;
        m = fmaxf(m, s);
    }
    for (int off = 32; off >= 1; off >>= 1) m = fmaxf(m, __shfl_xor(m, off));
    float sum = 0.f;
    for (int k = 0; k < n; ++k) { v[k] = expf(v[k] - m); sum += v[k]; }
    for (int off = 32; off >= 1; off >>= 1) sum += __shfl_xor(sum, off);
    float inv_s = 1.f / sum;
    for (int k = 0; k < n; ++k) {
        float w = v[k] * inv_s;
        unsigned int wb = __float_as_uint(w);
        unsigned short hi = (unsigned short)(wb >> 16);         // truncation split
        float whf = __uint_as_float(wb & 0xFFFF0000u);
        wh[cs[k]] = hi;
        wl[cs[k]] = (unsigned short)(__float_as_uint(w - whf) >> 16);
    }
    for (int c = 270 + lane; c < 288; c += 64) { wh[c] = 0; wl[c] = 0; }
}

// -------- Kernel 4: merge — out[b] = W @ x[b], 3-term split-bf16 MFMA --------
// block tile: 96 o x 128 t; 4 waves, each: 6 m-frags x disjoint 32-t slice (2 nf)
// BOTH x and W k-chunks staged via global_load_lds (linear dest, pre-swizzled
// global source, swizzled LDS read). W chunk staged once per BLOCK per k-step
// (was: per wave via VMEM) -> 4x less L1/VMEM traffic on W.
// grid (16 t, 3 o, 64 b); block 256. LDS 56KB -> 2 blocks/CU.
__global__ __launch_bounds__(256) void merge_kernel(
    const float* __restrict__ x,
    const unsigned short* __restrict__ Wh,
    const unsigned short* __restrict__ Wl,
    float* __restrict__ out)
{
    __shared__ float xs[2][32][128];                       // 32 KB
    __shared__ __align__(16) unsigned char wlds[2][12288]; // 24 KB: [h 6KB][l 6KB]
    const int tb = blockIdx.x, ob = blockIdx.y, b = blockIdx.z;
    const int t0 = tb * 128, o0 = ob * 96;
    const int tid = threadIdx.x;
    const int wid = tid >> 6, lane = tid & 63;
    const int wt = wid * 32;
    const int lhi = lane >> 4, llo = lane & 15;

    const float* xb = x + (size_t)b * 270 * 2000;
    const float* x_last = x + (size_t)64 * 270 * 2000 - 4;

    f32x4 acc[6][2];
    #pragma unroll
    for (int m = 0; m < 6; ++m)
        #pragma unroll
        for (int n = 0; n < 2; ++n) acc[m][n] = (f32x4){0.f, 0.f, 0.f, 0.f};

    // ---- staging (all via global_load_lds, linear LDS dest) ----
    // x: 32 rows of 512B; wave wid stages rows {p*4+wid} with 32 lanes each.
    // W: 12 chunks of 1KB (6 h + 6 l), wave wid stages chunks {wid*3..wid*3+2};
    //    chunk q covers rows 16*(q%6).. of Wh (q<6) / Wl (q>=6); lane->row r0+(lane>>2),
    //    16B-unit (lane&3); source k-unit pre-swizzled by ((lane>>3)&3).
    auto stage = [&](int buf, int ks) {
        if (lane < 32) {
            #pragma unroll
            for (int p = 0; p < 8; ++p) {
                int row = p * 4 + wid;
                int c = ks * 32 + row;
                if (c > 269) c = 269;                    // W k-pad is zero -> harmless
                int s = (row >> 2) & 7;
                const float* gp = xb + (size_t)c * 2000 + t0 + ((lane ^ s) << 2);
                if (gp > x_last) gp = x_last;            // in-bounds; masked at store
                __builtin_amdgcn_global_load_lds(
                    (const __attribute__((address_space(1))) u32*)gp,
                    (__attribute__((address_space(3))) u32*)&xs[buf][row][0],
                    16, 0, 0);
            }
        }
        #pragma unroll
        for (int i = 0; i < 3; ++i) {
            int q = wid * 3 + i;
            int half = (q >= 6);
            int chunk = half ? q - 6 : q;
            const unsigned short* Wsel = half ? Wl : Wh;
            int rloc = chunk * 16 + (lane >> 2);
            int gu = (lane & 3) ^ ((lane >> 3) & 3);     // source swizzle
            const unsigned short* gp = Wsel + (size_t)(o0 + rloc) * 288 + ks * 32 + gu * 8;
            __builtin_amdgcn_global_load_lds(
                (const __attribute__((address_space(1))) u32*)gp,
                (__attribute__((address_space(3))) u32*)&wlds[buf][q * 1024],
                16, 0, 0);
        }
    };

    stage(0, 0);
    __syncthreads();

    for (int ks = 0; ks < 9; ++ks) {
        const int cur = ks & 1;
        if (ks < 8) stage(cur ^ 1, ks + 1);   // async into other buffer

        // A fragments from LDS (swizzled read matches staged source swizzle)
        bf16x8 ah[6], al[6];
        {
            const unsigned char* wb0 = &wlds[cur][0];
            int ubase = (llo * 64) + (((lhi ^ ((llo >> 1) & 3))) << 4);
            #pragma unroll
            for (int m = 0; m < 6; ++m) {
                ah[m] = *(const bf16x8*)(wb0 + m * 1024 + ubase);
                al[m] = *(const bf16x8*)(wb0 + 6144 + m * 1024 + ubase);
            }
        }

        #pragma unroll
        for (int nf = 0; nf < 2; ++nf) {
            int tcol = wt + nf * 16 + llo;
            float xr[8];
            #pragma unroll
            for (int j = 0; j < 8; ++j) {
                int k = lhi * 8 + j;
                int cidx = tcol ^ (((k >> 2) & 7) << 2);  // matches source swizzle
                xr[j] = xs[cur][k][cidx];
            }
            // in-register split to bf16 high/low fragments (truncation split)
            union { u32 u[4]; bf16x8 v; } bh, bl;
            #pragma unroll
            for (int p = 0; p < 4; ++p) {
                u32 u0 = __float_as_uint(xr[2 * p]);
                u32 u1 = __float_as_uint(xr[2 * p + 1]);
                bh.u[p] = (u0 >> 16) | (u1 & 0xFFFF0000u);
                float h0 = __uint_as_float(u0 & 0xFFFF0000u);
                float h1 = __uint_as_float(u1 & 0xFFFF0000u);
                u32 l0 = __float_as_uint(xr[2 * p] - h0);
                u32 l1 = __float_as_uint(xr[2 * p + 1] - h1);
                bl.u[p] = (l0 >> 16) | (l1 & 0xFFFF0000u);
            }
            #pragma unroll
            for (int m = 0; m < 6; ++m) {
                acc[m][nf] = __builtin_amdgcn_mfma_f32_16x16x32_bf16(ah[m], bh.v, acc[m][nf], 0, 0, 0);
                acc[m][nf] = __builtin_amdgcn_mfma_f32_16x16x32_bf16(ah[m], bl.v, acc[m][nf], 0, 0, 0);
                acc[m][nf] = __builtin_amdgcn_mfma_f32_16x16x32_bf16(al[m], bh.v, acc[m][nf], 0, 0, 0);
            }
        }

        __syncthreads();   // drains GLL (vmcnt 0) + readers done before overwrite
    }

    // epilogue: D frag -> out; D[row=4*lhi+r][col=llo]
    const size_t ob_base = (size_t)b * 270 * 2000;
    #pragma unroll
    for (int m = 0; m < 6; ++m) {
        #pragma unroll
        for (int r = 0; r < 4; ++r) {
            int orow = o0 + m * 16 + lhi * 4 + r;
            if (orow < 270) {
                float* op = out + ob_base + (size_t)orow * 2000;
                #pragma unroll
                for (int nf = 0; nf < 2; ++nf) {
                    int t = t0 + wt + nf * 16 + llo;
                    if (t < 2000) op[t] = acc[m][nf][r];
                }
            }
        }
    }
}

extern "C" void kernel_launch(void* const* d_in, const int* in_sizes, int n_in,
                              void* d_out, int out_size, void* d_ws, size_t ws_size,
                              hipStream_t stream) {
    const float* x      = (const float*)d_in[0];
    const float* layout = (const float*)d_in[1];
    const float* heads  = (const float*)d_in[2];
    float* out = (float*)d_out;
    char* ws = (char*)d_ws;

    float* scores          = (float*)(ws + SCORES_OFF);
    unsigned short* Wh     = (unsigned short*)(ws + WH_OFF);
    unsigned short* Wl     = (unsigned short*)(ws + WL_OFF);
    unsigned short* embh   = (unsigned short*)(ws + EMBH_OFF);
    unsigned short* headsh = (unsigned short*)(ws + HEADSH_OFF);

    prep_kernel<<<540, 256, 0, stream>>>(layout, heads, embh, headsh);
    scores_kernel<<<dim3(9, 9), 256, 0, stream>>>(headsh, embh, scores);
    softmax_kernel<<<288, 64, 0, stream>>>(scores, layout, Wh, Wl);
    merge_kernel<<<dim3(16, 3, 64), 256, 0, stream>>>(x, Wh, Wl, out);
}